// Round 1
// baseline (19055.562 us; speedup 1.0000x reference)
//
#include <hip/hip_runtime.h>

// ---------------- types ----------------
typedef short bf16x8 __attribute__((ext_vector_type(8)));
typedef float f32x4 __attribute__((ext_vector_type(4)));

static __device__ __forceinline__ unsigned short f2bf(float f) {
    unsigned int u = __float_as_uint(f);
    unsigned int r = (u + 0x7fffu + ((u >> 16) & 1u)) >> 16;
    return (unsigned short)r;
}

static __device__ __forceinline__ float sigmoidf_(float x) {
    return 1.0f / (1.0f + __expf(-x));
}
static __device__ __forceinline__ float tanhf_(float x) {
    return 2.0f / (1.0f + __expf(-2.0f * x)) - 1.0f;
}

// ---------------- embedding gather: XT[t][d][b] = emb[seq[b][t]][d] ----------------
__global__ __launch_bounds__(256) void gather_embed(const int* __restrict__ seq,
                                                    const float* __restrict__ emb,
                                                    float* __restrict__ XT) {
    int t = blockIdx.x;          // 0..63
    int q = blockIdx.y;          // 0..3
    float* xt = XT + (size_t)t * 32768;
    int base = q * 8192;
    for (int i = 0; i < 32; i++) {
        int idx = base + i * 256 + threadIdx.x;   // 0..32767 element of [1024][32]
        int d = idx >> 5;
        int b = idx & 31;
        int row = seq[b * 64 + t];
        xt[idx] = emb[(size_t)row * 1024 + d];
    }
}

// ---------------- one mogrifier step: dstT = 2*sigmoid(gin @ W^T + bias) * srcT ----------------
// Activations transposed: [1024 dims][32 batch]
__global__ __launch_bounds__(256) void mog_step(const float* __restrict__ ginT,
                                                const float* __restrict__ W,
                                                const float* __restrict__ bias,
                                                const float* __restrict__ srcT,
                                                float* __restrict__ dstT) {
    int tid = threadIdx.x;
    int b  = tid & 31;
    int kh = (tid >> 5) & 1;     // k-half
    int jo = tid >> 6;           // 0..3
    int j  = blockIdx.x * 4 + jo;

    const float* wrow = W + (size_t)j * 1024 + kh * 512;
    const float* gp   = ginT + (size_t)kh * 512 * 32 + b;

    float a0 = 0.f, a1 = 0.f, a2 = 0.f, a3 = 0.f;
#pragma unroll 4
    for (int k = 0; k < 512; k += 4) {
        float4 w = *(const float4*)(wrow + k);
        a0 += gp[(k + 0) * 32] * w.x;
        a1 += gp[(k + 1) * 32] * w.y;
        a2 += gp[(k + 2) * 32] * w.z;
        a3 += gp[(k + 3) * 32] * w.w;
    }
    float s = (a0 + a1) + (a2 + a3);
    s += __shfl_xor(s, 32);
    if (kh == 0) {
        s += bias[j];
        float g = 2.0f * sigmoidf_(s);
        dstT[j * 32 + b] = g * srcT[j * 32 + b];
    }
}

// ---------------- LSTM cell ----------------
// g = x@W_ih^T + b_ih + hm@W_hh^T + b_hh ; gates i,f,g,o ; update c, h.
// Writes hT (transposed), optionally copyT (transposed) and hsOut (B,T,H layout).
__global__ __launch_bounds__(256) void lstm_cell(const float* __restrict__ xT,
                                                 const float* __restrict__ hmT,
                                                 const float* __restrict__ Wih,
                                                 const float* __restrict__ Whh,
                                                 const float* __restrict__ bih,
                                                 const float* __restrict__ bhh,
                                                 float* __restrict__ cT,
                                                 float* __restrict__ hT,
                                                 float* __restrict__ copyT,
                                                 float* __restrict__ hsOut,
                                                 int t) {
    int tid = threadIdx.x;
    int b  = tid & 31;
    int kh = (tid >> 5) & 1;
    int jo = tid >> 6;
    int j  = blockIdx.x * 4 + jo;

    const float* wi = Wih + (size_t)j * 1024 + kh * 512;
    const float* wh = Whh + (size_t)j * 1024 + kh * 512;
    const float* xp = xT  + (size_t)kh * 512 * 32 + b;
    const float* hp = hmT + (size_t)kh * 512 * 32 + b;

    float si = 0.f, sf = 0.f, sg = 0.f, so = 0.f;
#pragma unroll 2
    for (int k = 0; k < 512; k += 4) {
        float4 wii = *(const float4*)(wi + k);
        float4 wif = *(const float4*)(wi + 1048576 + k);
        float4 wig = *(const float4*)(wi + 2097152 + k);
        float4 wio = *(const float4*)(wi + 3145728 + k);
        float4 whi = *(const float4*)(wh + k);
        float4 whf = *(const float4*)(wh + 1048576 + k);
        float4 whg = *(const float4*)(wh + 2097152 + k);
        float4 who = *(const float4*)(wh + 3145728 + k);
        float x0 = xp[(k + 0) * 32], x1 = xp[(k + 1) * 32];
        float x2 = xp[(k + 2) * 32], x3 = xp[(k + 3) * 32];
        float h0 = hp[(k + 0) * 32], h1 = hp[(k + 1) * 32];
        float h2 = hp[(k + 2) * 32], h3 = hp[(k + 3) * 32];
        si += x0 * wii.x + x1 * wii.y + x2 * wii.z + x3 * wii.w;
        si += h0 * whi.x + h1 * whi.y + h2 * whi.z + h3 * whi.w;
        sf += x0 * wif.x + x1 * wif.y + x2 * wif.z + x3 * wif.w;
        sf += h0 * whf.x + h1 * whf.y + h2 * whf.z + h3 * whf.w;
        sg += x0 * wig.x + x1 * wig.y + x2 * wig.z + x3 * wig.w;
        sg += h0 * whg.x + h1 * whg.y + h2 * whg.z + h3 * whg.w;
        so += x0 * wio.x + x1 * wio.y + x2 * wio.z + x3 * wio.w;
        so += h0 * who.x + h1 * who.y + h2 * who.z + h3 * who.w;
    }
    si += __shfl_xor(si, 32);
    sf += __shfl_xor(sf, 32);
    sg += __shfl_xor(sg, 32);
    so += __shfl_xor(so, 32);
    if (kh == 0) {
        si += bih[j]        + bhh[j];
        sf += bih[j + 1024] + bhh[j + 1024];
        sg += bih[j + 2048] + bhh[j + 2048];
        so += bih[j + 3072] + bhh[j + 3072];
        float ig = sigmoidf_(si);
        float fg = sigmoidf_(sf);
        float gg = tanhf_(sg);
        float og = sigmoidf_(so);
        int idx = j * 32 + b;
        float c = fg * cT[idx] + ig * gg;
        cT[idx] = c;
        float h = og * tanhf_(c);
        hT[idx] = h;
        if (copyT) copyT[idx] = h;
        if (hsOut) hsOut[(size_t)b * 65536 + (size_t)t * 1024 + j] = h;
    }
}

// ---------------- fp32 -> bf16 ----------------
__global__ __launch_bounds__(256) void f32_to_bf16(const float* __restrict__ in,
                                                   unsigned short* __restrict__ out, int n) {
    int i = (blockIdx.x * 256 + threadIdx.x) * 8;
    if (i + 7 < n) {
        float4 f0 = *(const float4*)(in + i);
        float4 f1 = *(const float4*)(in + i + 4);
        bf16x8 v;
        v[0] = (short)f2bf(f0.x); v[1] = (short)f2bf(f0.y);
        v[2] = (short)f2bf(f0.z); v[3] = (short)f2bf(f0.w);
        v[4] = (short)f2bf(f1.x); v[5] = (short)f2bf(f1.y);
        v[6] = (short)f2bf(f1.z); v[7] = (short)f2bf(f1.w);
        *(bf16x8*)(out + i) = v;
    }
}

// ---------------- output projection: out[r][v] = hs[r] . emb[v] + fc_b[v] ----------------
// M=2048 (rows r=b*64+t), N=32000, K=1024.  A = hs_bf16 (row-major K-contig),
// B^T = emb (row-major K-contig, converted to bf16 inline during staging).
__global__ __launch_bounds__(256) void out_proj(const unsigned short* __restrict__ hsb,
                                                const float* __restrict__ emb,
                                                const float* __restrict__ fcb,
                                                float* __restrict__ out) {
    __shared__ unsigned short Al[128 * 40];  // row stride 40 shorts (80B): 16B aligned, ~2-way banks
    __shared__ unsigned short Bl[128 * 40];
    int tid = threadIdx.x;
    int n0 = blockIdx.x * 128;
    int m0 = blockIdx.y * 128;
    int wid = tid >> 6, l = tid & 63;
    int wm = wid >> 1, wn = wid & 1;
    int c16 = l & 15, kg = l >> 4;

    f32x4 acc[4][4];
#pragma unroll
    for (int i = 0; i < 4; i++)
#pragma unroll
        for (int j = 0; j < 4; j++) acc[i][j] = (f32x4){0.f, 0.f, 0.f, 0.f};

    for (int k0 = 0; k0 < 1024; k0 += 32) {
        // stage A (128 rows x 32 k, bf16)
#pragma unroll
        for (int i = 0; i < 2; i++) {
            int id = i * 256 + tid;           // 0..511
            int r = id >> 2, c = id & 3;
            *(bf16x8*)&Al[r * 40 + c * 8] =
                *(const bf16x8*)(hsb + (size_t)(m0 + r) * 1024 + k0 + c * 8);
        }
        // stage B with inline fp32->bf16 convert
#pragma unroll
        for (int i = 0; i < 2; i++) {
            int id = i * 256 + tid;
            int r = id >> 2, c = id & 3;
            const float* src = emb + (size_t)(n0 + r) * 1024 + k0 + c * 8;
            float4 f0 = *(const float4*)(src);
            float4 f1 = *(const float4*)(src + 4);
            bf16x8 v;
            v[0] = (short)f2bf(f0.x); v[1] = (short)f2bf(f0.y);
            v[2] = (short)f2bf(f0.z); v[3] = (short)f2bf(f0.w);
            v[4] = (short)f2bf(f1.x); v[5] = (short)f2bf(f1.y);
            v[6] = (short)f2bf(f1.z); v[7] = (short)f2bf(f1.w);
            *(bf16x8*)&Bl[r * 40 + c * 8] = v;
        }
        __syncthreads();

        bf16x8 afr[4], bfr[4];
#pragma unroll
        for (int i = 0; i < 4; i++)
            afr[i] = *(const bf16x8*)&Al[(wm * 64 + i * 16 + c16) * 40 + kg * 8];
#pragma unroll
        for (int j = 0; j < 4; j++)
            bfr[j] = *(const bf16x8*)&Bl[(wn * 64 + j * 16 + c16) * 40 + kg * 8];
#pragma unroll
        for (int i = 0; i < 4; i++)
#pragma unroll
            for (int j = 0; j < 4; j++)
                acc[i][j] = __builtin_amdgcn_mfma_f32_16x16x32_bf16(afr[i], bfr[j], acc[i][j], 0, 0, 0);
        __syncthreads();
    }

    // epilogue: C/D layout col = lane&15, row = (lane>>4)*4 + reg
#pragma unroll
    for (int i = 0; i < 4; i++) {
        int row = m0 + wm * 64 + i * 16 + kg * 4;
#pragma unroll
        for (int j = 0; j < 4; j++) {
            int col = n0 + wn * 64 + j * 16 + c16;
            float fb = fcb[col];
#pragma unroll
            for (int r = 0; r < 4; r++)
                out[(size_t)(row + r) * 32000 + col] = acc[i][j][r] + fb;
        }
    }
}

// ---------------- host ----------------
extern "C" void kernel_launch(void* const* d_in, const int* in_sizes, int n_in,
                              void* d_out, int out_size, void* d_ws, size_t ws_size,
                              hipStream_t stream) {
    const int*   seq    = (const int*)d_in[0];
    const float* emb    = (const float*)d_in[2];
    const float* mog1_W = (const float*)d_in[3];
    const float* mog1_b = (const float*)d_in[4];
    const float* W_ih1  = (const float*)d_in[5];
    const float* W_hh1  = (const float*)d_in[6];
    const float* b_ih1  = (const float*)d_in[7];
    const float* b_hh1  = (const float*)d_in[8];
    const float* mog2_W = (const float*)d_in[9];
    const float* mog2_b = (const float*)d_in[10];
    const float* W_ih2  = (const float*)d_in[11];
    const float* W_hh2  = (const float*)d_in[12];
    const float* b_ih2  = (const float*)d_in[13];
    const float* b_hh2  = (const float*)d_in[14];
    const float* fc_b   = (const float*)d_in[15];

    char* ws = (char*)d_ws;
    float* XT  = (float*)(ws);                       // 64 x [1024][32] = 8 MB
    float* h1T = (float*)(ws + 8388608);             // [1024][32]
    float* c1T = (float*)(ws + 8519680);
    float* h2T = (float*)(ws + 8650752);
    float* c2T = (float*)(ws + 8781824);
    float* hmT = (float*)(ws + 8912896);
    float* x2T = (float*)(ws + 9043968);
    unsigned short* hsb = (unsigned short*)(ws + 9175040);  // [2048][1024] bf16

    float* out0 = (float*)d_out;                  // (B,T,V) fp32
    float* hs   = out0 + 65536000LL;              // (B,T,H) fp32 (output 1)

    // zero h1,c1,h2,c2 (contiguous)
    hipMemsetAsync(h1T, 0, 4 * 131072, stream);

    gather_embed<<<dim3(64, 4), 256, 0, stream>>>(seq, emb, XT);

    for (int t = 0; t < 64; t++) {
        float* xt = XT + (size_t)t * 32768;
        // layer 1 mogrifier (i=0..4): even i -> x update, odd i -> h update
        mog_step<<<256, 256, 0, stream>>>(h1T, mog1_W + 0 * 1048576, mog1_b + 0,    xt,  xt);
        mog_step<<<256, 256, 0, stream>>>(xt,  mog1_W + 1 * 1048576, mog1_b + 1024, h1T, hmT);
        mog_step<<<256, 256, 0, stream>>>(hmT, mog1_W + 2 * 1048576, mog1_b + 2048, xt,  xt);
        mog_step<<<256, 256, 0, stream>>>(xt,  mog1_W + 3 * 1048576, mog1_b + 3072, hmT, hmT);
        mog_step<<<256, 256, 0, stream>>>(hmT, mog1_W + 4 * 1048576, mog1_b + 4096, xt,  xt);
        lstm_cell<<<256, 256, 0, stream>>>(xt, hmT, W_ih1, W_hh1, b_ih1, b_hh1,
                                           c1T, h1T, x2T, (float*)nullptr, t);
        // layer 2 mogrifier on (x2 = h1 copy, h2)
        mog_step<<<256, 256, 0, stream>>>(h2T, mog2_W + 0 * 1048576, mog2_b + 0,    x2T, x2T);
        mog_step<<<256, 256, 0, stream>>>(x2T, mog2_W + 1 * 1048576, mog2_b + 1024, h2T, hmT);
        mog_step<<<256, 256, 0, stream>>>(hmT, mog2_W + 2 * 1048576, mog2_b + 2048, x2T, x2T);
        mog_step<<<256, 256, 0, stream>>>(x2T, mog2_W + 3 * 1048576, mog2_b + 3072, hmT, hmT);
        mog_step<<<256, 256, 0, stream>>>(hmT, mog2_W + 4 * 1048576, mog2_b + 4096, x2T, x2T);
        lstm_cell<<<256, 256, 0, stream>>>(x2T, hmT, W_ih2, W_hh2, b_ih2, b_hh2,
                                           c2T, h2T, (float*)nullptr, hs, t);
    }

    // hidden states -> bf16, then big projection
    f32_to_bf16<<<1024, 256, 0, stream>>>(hs, hsb, 2097152);
    out_proj<<<dim3(250, 16), 256, 0, stream>>>(hsb, emb, fc_b, out0);
}